// Round 1
// 594.984 us; speedup vs baseline: 1.2841x; 1.2841x over previous
//
#include <hip/hip_runtime.h>
#include <stdint.h>

// ---------- types ----------
typedef __attribute__((ext_vector_type(8))) short short8;
typedef __attribute__((ext_vector_type(4))) float floatx4;

__device__ inline float bf2f(unsigned short u) {
  union { unsigned int i; float f; } v; v.i = ((unsigned int)u) << 16; return v.f;
}
__device__ inline unsigned short f2bf(float f) {
  union { float f; unsigned int i; } v; v.f = f;
  unsigned int r = v.i + 0x7FFFu + ((v.i >> 16) & 1u);  // round-nearest-even
  return (unsigned short)(r >> 16);
}

// ---------- utility ----------
__global__ void zero_i32(int* __restrict__ p, int n) {
  int i = blockIdx.x * blockDim.x + threadIdx.x;
  if (i < n) p[i] = 0;
}

// ---- CSR build, pass 1: per-(dst,rel) histogram; atomic return value IS the
//      edge's rank within its bin (order nondeterministic, but we only sum). ----
__global__ void count_rank(const int* __restrict__ dst, const int* __restrict__ et,
                           int* __restrict__ cnt, unsigned short* __restrict__ rank,
                           int E) {
  int e = blockIdx.x * blockDim.x + threadIdx.x;
  if (e < E) {
    int idx = dst[e] * 8 + et[e];
    rank[e] = (unsigned short)atomicAdd(&cnt[idx], 1);
  }
}

// inv[i] = 1/max(cnt[i],1)  (mean weights; no atomic float accumulation needed)
__global__ void invert_cnt(const int* __restrict__ cnt, float* __restrict__ inv, int n) {
  int i = blockIdx.x * blockDim.x + threadIdx.x;
  if (i < n) inv[i] = 1.0f / fmaxf((float)cnt[i], 1.0f);
}

// ---------- exclusive scan of cnt[n2] -> eptr8[n2] (+eptr8[n2]=E) ----------
#define SCAN_T 256
#define SCAN_E 4   // 1024 elems per block

__global__ void scan1(const int* __restrict__ cnt, int* __restrict__ bsum, int n) {
  __shared__ int lds[SCAN_T];
  int base = blockIdx.x * (SCAN_T * SCAN_E);
  int tid = threadIdx.x;
  int s = 0;
#pragma unroll
  for (int j = 0; j < SCAN_E; ++j) {
    int i = base + tid * SCAN_E + j;
    if (i < n) s += cnt[i];
  }
  lds[tid] = s; __syncthreads();
  for (int off = SCAN_T / 2; off > 0; off >>= 1) {
    if (tid < off) lds[tid] += lds[tid + off];
    __syncthreads();
  }
  if (tid == 0) bsum[blockIdx.x] = lds[0];
}

// parallel single-block exclusive scan over bsum[nb] (nb <= 1024)
__global__ void scan2(int* __restrict__ bsum, int* __restrict__ eptr, int nb, int n) {
  __shared__ int lds[SCAN_T];
  int tid = threadIdx.x;
  int loc[4]; int s = 0;
#pragma unroll
  for (int j = 0; j < 4; ++j) {
    int i = tid * 4 + j;
    loc[j] = (i < nb) ? bsum[i] : 0; s += loc[j];
  }
  lds[tid] = s; __syncthreads();
  for (int off = 1; off < SCAN_T; off <<= 1) {   // Hillis-Steele inclusive
    int v = (tid >= off) ? lds[tid - off] : 0;
    __syncthreads();
    lds[tid] += v;
    __syncthreads();
  }
  int run = (tid > 0 ? lds[tid - 1] : 0);
#pragma unroll
  for (int j = 0; j < 4; ++j) {
    int i = tid * 4 + j;
    if (i < nb) { int v = loc[j]; bsum[i] = run; run += v; }
  }
  if (tid == 0) eptr[n] = lds[SCAN_T - 1];   // total = E
}

__global__ void scan3(const int* __restrict__ cnt, const int* __restrict__ bsum,
                      int* __restrict__ eptr, int n) {
  __shared__ int lds[SCAN_T];
  int base = blockIdx.x * (SCAN_T * SCAN_E);
  int tid = threadIdx.x;
  int loc[SCAN_E]; int s = 0;
#pragma unroll
  for (int j = 0; j < SCAN_E; ++j) {
    int i = base + tid * SCAN_E + j;
    loc[j] = (i < n) ? cnt[i] : 0; s += loc[j];
  }
  lds[tid] = s; __syncthreads();
  for (int off = 1; off < SCAN_T; off <<= 1) {   // Hillis-Steele inclusive
    int v = (tid >= off) ? lds[tid - off] : 0;
    __syncthreads();
    lds[tid] += v;
    __syncthreads();
  }
  int run = (tid > 0 ? lds[tid - 1] : 0) + bsum[blockIdx.x];
#pragma unroll
  for (int j = 0; j < SCAN_E; ++j) {
    int i = base + tid * SCAN_E + j;
    if (i < n) { eptr[i] = run; run += loc[j]; }
  }
}

// ---- CSR build, pass 2: deterministic placement, NO atomics.
//      position = eptr8[d*8+r] + rank[e]; entry = (src<<3)|rel ----
__global__ void scatter_edges(const int* __restrict__ src, const int* __restrict__ dst,
                              const int* __restrict__ et, const int* __restrict__ eptr8,
                              const unsigned short* __restrict__ rank,
                              unsigned* __restrict__ entry, int E) {
  int e = blockIdx.x * blockDim.x + threadIdx.x;
  if (e < E) {
    int d = dst[e], r = et[e];
    int p = eptr8[d * 8 + r] + (int)rank[e];
    entry[p] = ((unsigned)src[e] << 3) | (unsigned)r;
  }
}

// ---------- transform: Y[n][g*64+c] = sum_d act(X[n][d]) * W_g[d][c]  (g<R, bf16 out)
// ----------            acc[n][c]    = b[c] + sum_d act(X[n][d]) * root[d][c] (g==R)
// act = relu if relu_in (layer 2 reads layer-1 acc directly; fused relu).
// MFMA 16x16x32 bf16; A/B/C layouts per m89/m91.
__global__ void __launch_bounds__(256)
transform(const float* __restrict__ X, const float* __restrict__ W,
          const float* __restrict__ root, const float* __restrict__ bias,
          unsigned short* __restrict__ Y, float* __restrict__ acc, int N, int R,
          int relu_in)
{
  const int g    = blockIdx.y;            // 0..R  (R == root/bias group)
  const int lane = threadIdx.x & 63;
  const int wave = threadIdx.x >> 6;
  const int lc   = lane & 15;
  const int quad = lane >> 4;
  const float* B = (g < R) ? (W + (size_t)g * 64 * 64) : root;

  short8 bfrag[2][4];
#pragma unroll
  for (int kc = 0; kc < 2; ++kc)
#pragma unroll
    for (int nt = 0; nt < 4; ++nt) {
      short8 f;
#pragma unroll
      for (int j = 0; j < 8; ++j)
        f[j] = (short)f2bf(B[(size_t)(kc * 32 + quad * 8 + j) * 64 + nt * 16 + lc]);
      bfrag[kc][nt] = f;
    }

  const int tiles  = (N + 15) >> 4;
  const int stride = gridDim.x * 4;
  for (int t = blockIdx.x * 4 + wave; t < tiles; t += stride) {
    const int nb  = t << 4;
    const int row = min(nb + lc, N - 1);
    const float* xr = X + (size_t)row * 64;
    short8 a0, a1;
#pragma unroll
    for (int j = 0; j < 8; ++j) {
      float v0 = xr[quad * 8 + j];
      float v1 = xr[32 + quad * 8 + j];
      if (relu_in) { v0 = fmaxf(v0, 0.f); v1 = fmaxf(v1, 0.f); }
      a0[j] = (short)f2bf(v0);
      a1[j] = (short)f2bf(v1);
    }
#pragma unroll
    for (int nt = 0; nt < 4; ++nt) {
      floatx4 d = {0.f, 0.f, 0.f, 0.f};
      d = __builtin_amdgcn_mfma_f32_16x16x32_bf16(a0, bfrag[0][nt], d, 0, 0, 0);
      d = __builtin_amdgcn_mfma_f32_16x16x32_bf16(a1, bfrag[1][nt], d, 0, 0, 0);
      const int c = nt * 16 + lc;
      if (g < R) {
#pragma unroll
        for (int i = 0; i < 4; ++i) {
          int r_ = nb + quad * 4 + i;
          if (r_ < N) Y[(size_t)r_ * (R * 64) + g * 64 + c] = f2bf(d[i]);
        }
      } else {
        float bv = bias[c];
#pragma unroll
        for (int i = 0; i < 4; ++i) {
          int r_ = nb + quad * 4 + i;
          if (r_ < N) acc[(size_t)r_ * 64 + c] = d[i] + bv;
        }
      }
    }
  }
}

// ---------- CSR edge aggregation: one wave owns one dst node. No atomics.
// acc[d][lane] += sum_{e in seg(d)} Y[src_e][rel_e*64+lane] * inv[d*8+rel_e]
__global__ void __launch_bounds__(256)
edge_agg_csr(const unsigned short* __restrict__ Y, const int* __restrict__ eptr8,
             const unsigned* __restrict__ entry, const float* __restrict__ inv,
             float* __restrict__ acc, int N)
{
  const int wid  = (blockIdx.x * blockDim.x + threadIdx.x) >> 6;
  const int lane = threadIdx.x & 63;
  if (wid >= N) return;
  const int lo = eptr8[wid * 8], hi = eptr8[wid * 8 + 8];
  const float invv = inv[(size_t)wid * 8 + (lane & 7)];   // lanes 0..7 hold the 8 rel weights
  float sum = 0.f;
  int e = lo;
  for (; e + 4 <= hi; e += 4) {
    unsigned en0 = entry[e], en1 = entry[e + 1], en2 = entry[e + 2], en3 = entry[e + 3];
    float v0 = bf2f(Y[(size_t)(en0 >> 3) * 512 + (en0 & 7) * 64 + lane]);
    float v1 = bf2f(Y[(size_t)(en1 >> 3) * 512 + (en1 & 7) * 64 + lane]);
    float v2 = bf2f(Y[(size_t)(en2 >> 3) * 512 + (en2 & 7) * 64 + lane]);
    float v3 = bf2f(Y[(size_t)(en3 >> 3) * 512 + (en3 & 7) * 64 + lane]);
    sum += v0 * __shfl(invv, (int)(en0 & 7)) + v1 * __shfl(invv, (int)(en1 & 7))
         + v2 * __shfl(invv, (int)(en2 & 7)) + v3 * __shfl(invv, (int)(en3 & 7));
  }
  for (; e < hi; ++e) {
    unsigned en = entry[e];
    float v = bf2f(Y[(size_t)(en >> 3) * 512 + (en & 7) * 64 + lane]);
    sum += v * __shfl(invv, (int)(en & 7));
  }
  acc[(size_t)wid * 64 + lane] += sum;
}

// graph segment boundaries from sorted batch: glo[g] = lower_bound(batch, g); glo[G]=N
__global__ void glo_bounds(const int* __restrict__ batch, int* __restrict__ glo,
                           int N, int G) {
  int g = blockIdx.x * blockDim.x + threadIdx.x;
  if (g > G) return;
  if (g == G) { glo[G] = N; return; }
  int lo = 0, hi = N;
  while (lo < hi) { int mid = (lo + hi) >> 1; if (batch[mid] < g) lo = mid + 1; else hi = mid; }
  glo[g] = lo;
}

// fused mean-pool + finalize: one block per graph, contiguous node segment
__global__ void __launch_bounds__(256)
pool(const float* __restrict__ acc, const int* __restrict__ glo,
     float* __restrict__ out, int G)
{
  const int g = blockIdx.x;
  const int lane = threadIdx.x & 63;
  const int w = threadIdx.x >> 6;
  const int lo = glo[g], hi = glo[g + 1];
  float s = 0.f;
  for (int n = lo + w; n < hi; n += 4) s += acc[(size_t)n * 64 + lane];
  __shared__ float red[4][64];
  red[w][lane] = s;
  __syncthreads();
  if (w == 0) {
    float t = red[0][lane] + red[1][lane] + red[2][lane] + red[3][lane];
    out[(size_t)g * 64 + lane] = t / fmaxf((float)(hi - lo), 1.0f);
  }
}

// ---------- launch ----------
extern "C" void kernel_launch(void* const* d_in, const int* in_sizes, int n_in,
                              void* d_out, int out_size, void* d_ws, size_t ws_size,
                              hipStream_t stream)
{
  const float* x     = (const float*)d_in[0];
  const int*   ei    = (const int*)d_in[1];
  const int*   etype = (const int*)d_in[2];
  const int*   batch = (const int*)d_in[3];
  const float* W1    = (const float*)d_in[4];
  const float* root1 = (const float*)d_in[5];
  const float* b1    = (const float*)d_in[6];
  const float* W2    = (const float*)d_in[7];
  const float* root2 = (const float*)d_in[8];
  const float* b2    = (const float*)d_in[9];

  const int N = in_sizes[0] / 64;
  const int E = in_sizes[1] / 2;
  const int R = in_sizes[4] / (64 * 64);
  const int G = out_size / 64;
  const int* srcp = ei;
  const int* dstp = ei + E;
  const int n2 = N * R;   // (dst,rel) bins

  // workspace carve-up (256B aligned)
  char* ws = (char*)d_ws;
  size_t off = 0;
  auto carve = [&](size_t bytes) -> void* {
    void* p = ws + off; off = (off + bytes + 255) & ~(size_t)255; return p;
  };
  float*          inv   = (float*)carve((size_t)n2 * 4);
  float*          accA  = (float*)carve((size_t)N * 64 * 4);
  float*          accB  = (float*)carve((size_t)N * 64 * 4);
  unsigned short* Y     = (unsigned short*)carve((size_t)N * R * 64 * 2);
  int*            eptr8 = (int*)carve((size_t)(n2 + 1) * 4);
  unsigned*       entry = (unsigned*)carve((size_t)E * 4);
  int*            bsum  = (int*)carve(1024 * 4);
  int*            glo   = (int*)carve((size_t)(G + 1) * 4);
  // dead-before-first-write aliases (same stream ⇒ ordered):
  //   rank[E] (u16) lives only until scatter_edges; accA first written by transform L1.
  //   cnt[n2] (i32) lives only until scan3/invert;  accB first written by transform L2.
  unsigned short* rank = (unsigned short*)accA;
  int*            cnt  = (int*)accB;
  (void)ws_size; (void)n_in;

  const int nb2 = (n2 + SCAN_T * SCAN_E - 1) / (SCAN_T * SCAN_E);

  // ---- CSR build: 1 atomic per edge total ----
  zero_i32<<<(n2 + 255) / 256, 256, 0, stream>>>(cnt, n2);
  count_rank<<<(E + 255) / 256, 256, 0, stream>>>(dstp, etype, cnt, rank, E);
  invert_cnt<<<(n2 + 255) / 256, 256, 0, stream>>>(cnt, inv, n2);
  scan1<<<nb2, SCAN_T, 0, stream>>>(cnt, bsum, n2);
  scan2<<<1, SCAN_T, 0, stream>>>(bsum, eptr8, nb2, n2);
  scan3<<<nb2, SCAN_T, 0, stream>>>(cnt, bsum, eptr8, n2);
  scatter_edges<<<(E + 255) / 256, 256, 0, stream>>>(srcp, dstp, etype, eptr8, rank, entry, E);

  dim3 tgrid(128, R + 1);
  const int aggBlocks = (N * 64 + 255) / 256;

  // ---- layer 1 ----
  transform<<<tgrid, 256, 0, stream>>>(x, W1, root1, b1, Y, accA, N, R, 0);
  edge_agg_csr<<<aggBlocks, 256, 0, stream>>>(Y, eptr8, entry, inv, accA, N);

  // ---- layer 2 (relu fused into transform's input read) ----
  transform<<<tgrid, 256, 0, stream>>>(accA, W2, root2, b2, Y, accB, N, R, 1);
  edge_agg_csr<<<aggBlocks, 256, 0, stream>>>(Y, eptr8, entry, inv, accB, N);

  // ---- global mean pool (fused finalize) ----
  glo_bounds<<<1, 128, 0, stream>>>(batch, glo, N, G);
  pool<<<G, 256, 0, stream>>>(accB, glo, (float*)d_out, G);
}

// Round 2
// 506.330 us; speedup vs baseline: 1.5090x; 1.1751x over previous
//
#include <hip/hip_runtime.h>
#include <stdint.h>

// ---------- types ----------
typedef __attribute__((ext_vector_type(8))) short short8;
typedef __attribute__((ext_vector_type(4))) float floatx4;

__device__ inline float bf2f(unsigned short u) {
  union { unsigned int i; float f; } v; v.i = ((unsigned int)u) << 16; return v.f;
}
__device__ inline unsigned short f2bf(float f) {
  union { float f; unsigned int i; } v; v.f = f;
  unsigned int r = v.i + 0x7FFFu + ((v.i >> 16) & 1u);  // round-nearest-even
  return (unsigned short)(r >> 16);
}

// ---------- utility ----------
__global__ void zero_i32(int* __restrict__ p, int n) {
  int i = blockIdx.x * blockDim.x + threadIdx.x;
  if (i < n) p[i] = 0;
}

// ---- CSR build, pass 1: per-(dst,rel) histogram; atomic return value IS the
//      edge's rank within its bin (order nondeterministic, but we only sum). ----
__global__ void count_rank(const int* __restrict__ dst, const int* __restrict__ et,
                           int* __restrict__ cnt, unsigned short* __restrict__ rank,
                           int E) {
  int e = blockIdx.x * blockDim.x + threadIdx.x;
  if (e < E) {
    int idx = dst[e] * 8 + et[e];
    rank[e] = (unsigned short)atomicAdd(&cnt[idx], 1);
  }
}

// inv[i] = 1/max(cnt[i],1)  (mean weights; no atomic float accumulation needed)
__global__ void invert_cnt(const int* __restrict__ cnt, float* __restrict__ inv, int n) {
  int i = blockIdx.x * blockDim.x + threadIdx.x;
  if (i < n) inv[i] = 1.0f / fmaxf((float)cnt[i], 1.0f);
}

// ---------- exclusive scan of cnt[n2] -> eptr8[n2] (+eptr8[n2]=E) ----------
#define SCAN_T 256
#define SCAN_E 4   // 1024 elems per block

__global__ void scan1(const int* __restrict__ cnt, int* __restrict__ bsum, int n) {
  __shared__ int lds[SCAN_T];
  int base = blockIdx.x * (SCAN_T * SCAN_E);
  int tid = threadIdx.x;
  int s = 0;
#pragma unroll
  for (int j = 0; j < SCAN_E; ++j) {
    int i = base + tid * SCAN_E + j;
    if (i < n) s += cnt[i];
  }
  lds[tid] = s; __syncthreads();
  for (int off = SCAN_T / 2; off > 0; off >>= 1) {
    if (tid < off) lds[tid] += lds[tid + off];
    __syncthreads();
  }
  if (tid == 0) bsum[blockIdx.x] = lds[0];
}

// parallel single-block exclusive scan over bsum[nb] (nb <= 1024)
__global__ void scan2(int* __restrict__ bsum, int* __restrict__ eptr, int nb, int n) {
  __shared__ int lds[SCAN_T];
  int tid = threadIdx.x;
  int loc[4]; int s = 0;
#pragma unroll
  for (int j = 0; j < 4; ++j) {
    int i = tid * 4 + j;
    loc[j] = (i < nb) ? bsum[i] : 0; s += loc[j];
  }
  lds[tid] = s; __syncthreads();
  for (int off = 1; off < SCAN_T; off <<= 1) {   // Hillis-Steele inclusive
    int v = (tid >= off) ? lds[tid - off] : 0;
    __syncthreads();
    lds[tid] += v;
    __syncthreads();
  }
  int run = (tid > 0 ? lds[tid - 1] : 0);
#pragma unroll
  for (int j = 0; j < 4; ++j) {
    int i = tid * 4 + j;
    if (i < nb) { int v = loc[j]; bsum[i] = run; run += v; }
  }
  if (tid == 0) eptr[n] = lds[SCAN_T - 1];   // total = E
}

__global__ void scan3(const int* __restrict__ cnt, const int* __restrict__ bsum,
                      int* __restrict__ eptr, int n) {
  __shared__ int lds[SCAN_T];
  int base = blockIdx.x * (SCAN_T * SCAN_E);
  int tid = threadIdx.x;
  int loc[SCAN_E]; int s = 0;
#pragma unroll
  for (int j = 0; j < SCAN_E; ++j) {
    int i = base + tid * SCAN_E + j;
    loc[j] = (i < n) ? cnt[i] : 0; s += loc[j];
  }
  lds[tid] = s; __syncthreads();
  for (int off = 1; off < SCAN_T; off <<= 1) {   // Hillis-Steele inclusive
    int v = (tid >= off) ? lds[tid - off] : 0;
    __syncthreads();
    lds[tid] += v;
    __syncthreads();
  }
  int run = (tid > 0 ? lds[tid - 1] : 0) + bsum[blockIdx.x];
#pragma unroll
  for (int j = 0; j < SCAN_E; ++j) {
    int i = base + tid * SCAN_E + j;
    if (i < n) { eptr[i] = run; run += loc[j]; }
  }
}

// ---- CSR build, pass 2: deterministic placement, NO atomics.
//      position = eptr8[d*8+r] + rank[e]; entry = (src<<3)|rel ----
__global__ void scatter_edges(const int* __restrict__ src, const int* __restrict__ dst,
                              const int* __restrict__ et, const int* __restrict__ eptr8,
                              const unsigned short* __restrict__ rank,
                              unsigned* __restrict__ entry, int E) {
  int e = blockIdx.x * blockDim.x + threadIdx.x;
  if (e < E) {
    int d = dst[e], r = et[e];
    int p = eptr8[d * 8 + r] + (int)rank[e];
    entry[p] = ((unsigned)src[e] << 3) | (unsigned)r;
  }
}

// ---------- transform: Y[n][g*64+c] = sum_d act(X[n][d]) * W_g[d][c]  (g<R, bf16 out)
// ----------            acc[n][c]    = b[c] + sum_d act(X[n][d]) * root[d][c] (g==R)
// act = relu if relu_in (layer 2 reads layer-1 acc directly; fused relu).
// MFMA 16x16x32 bf16; A/B/C layouts per m89/m91.
__global__ void __launch_bounds__(256)
transform(const float* __restrict__ X, const float* __restrict__ W,
          const float* __restrict__ root, const float* __restrict__ bias,
          unsigned short* __restrict__ Y, float* __restrict__ acc, int N, int R,
          int relu_in)
{
  const int g    = blockIdx.y;            // 0..R  (R == root/bias group)
  const int lane = threadIdx.x & 63;
  const int wave = threadIdx.x >> 6;
  const int lc   = lane & 15;
  const int quad = lane >> 4;
  const float* B = (g < R) ? (W + (size_t)g * 64 * 64) : root;

  short8 bfrag[2][4];
#pragma unroll
  for (int kc = 0; kc < 2; ++kc)
#pragma unroll
    for (int nt = 0; nt < 4; ++nt) {
      short8 f;
#pragma unroll
      for (int j = 0; j < 8; ++j)
        f[j] = (short)f2bf(B[(size_t)(kc * 32 + quad * 8 + j) * 64 + nt * 16 + lc]);
      bfrag[kc][nt] = f;
    }

  const int tiles  = (N + 15) >> 4;
  const int stride = gridDim.x * 4;
  for (int t = blockIdx.x * 4 + wave; t < tiles; t += stride) {
    const int nb  = t << 4;
    const int row = min(nb + lc, N - 1);
    const float* xr = X + (size_t)row * 64;
    short8 a0, a1;
#pragma unroll
    for (int j = 0; j < 8; ++j) {
      float v0 = xr[quad * 8 + j];
      float v1 = xr[32 + quad * 8 + j];
      if (relu_in) { v0 = fmaxf(v0, 0.f); v1 = fmaxf(v1, 0.f); }
      a0[j] = (short)f2bf(v0);
      a1[j] = (short)f2bf(v1);
    }
#pragma unroll
    for (int nt = 0; nt < 4; ++nt) {
      floatx4 d = {0.f, 0.f, 0.f, 0.f};
      d = __builtin_amdgcn_mfma_f32_16x16x32_bf16(a0, bfrag[0][nt], d, 0, 0, 0);
      d = __builtin_amdgcn_mfma_f32_16x16x32_bf16(a1, bfrag[1][nt], d, 0, 0, 0);
      const int c = nt * 16 + lc;
      if (g < R) {
#pragma unroll
        for (int i = 0; i < 4; ++i) {
          int r_ = nb + quad * 4 + i;
          if (r_ < N) Y[(size_t)r_ * (R * 64) + g * 64 + c] = f2bf(d[i]);
        }
      } else {
        float bv = bias[c];
#pragma unroll
        for (int i = 0; i < 4; ++i) {
          int r_ = nb + quad * 4 + i;
          if (r_ < N) acc[(size_t)r_ * 64 + c] = d[i] + bv;
        }
      }
    }
  }
}

// ---------- CSR edge aggregation: one wave owns one dst node. No atomics.
// acc[d][lane] += sum_{e in seg(d)} Y[src_e][rel_e*64+lane] * inv[d*8+rel_e]
__global__ void __launch_bounds__(256)
edge_agg_csr(const unsigned short* __restrict__ Y, const int* __restrict__ eptr8,
             const unsigned* __restrict__ entry, const float* __restrict__ inv,
             float* __restrict__ acc, int N)
{
  const int wid  = (blockIdx.x * blockDim.x + threadIdx.x) >> 6;
  const int lane = threadIdx.x & 63;
  if (wid >= N) return;
  const int lo = eptr8[wid * 8], hi = eptr8[wid * 8 + 8];
  const float invv = inv[(size_t)wid * 8 + (lane & 7)];   // lanes 0..7 hold the 8 rel weights
  float sum = 0.f;
  int e = lo;
  for (; e + 4 <= hi; e += 4) {
    unsigned en0 = entry[e], en1 = entry[e + 1], en2 = entry[e + 2], en3 = entry[e + 3];
    float v0 = bf2f(Y[(size_t)(en0 >> 3) * 512 + (en0 & 7) * 64 + lane]);
    float v1 = bf2f(Y[(size_t)(en1 >> 3) * 512 + (en1 & 7) * 64 + lane]);
    float v2 = bf2f(Y[(size_t)(en2 >> 3) * 512 + (en2 & 7) * 64 + lane]);
    float v3 = bf2f(Y[(size_t)(en3 >> 3) * 512 + (en3 & 7) * 64 + lane]);
    sum += v0 * __shfl(invv, (int)(en0 & 7)) + v1 * __shfl(invv, (int)(en1 & 7))
         + v2 * __shfl(invv, (int)(en2 & 7)) + v3 * __shfl(invv, (int)(en3 & 7));
  }
  for (; e < hi; ++e) {
    unsigned en = entry[e];
    float v = bf2f(Y[(size_t)(en >> 3) * 512 + (en & 7) * 64 + lane]);
    sum += v * __shfl(invv, (int)(en & 7));
  }
  acc[(size_t)wid * 64 + lane] += sum;
}

// graph segment boundaries from sorted batch: glo[g] = lower_bound(batch, g); glo[G]=N
__global__ void glo_bounds(const int* __restrict__ batch, int* __restrict__ glo,
                           int N, int G) {
  int g = blockIdx.x * blockDim.x + threadIdx.x;
  if (g > G) return;
  if (g == G) { glo[G] = N; return; }
  int lo = 0, hi = N;
  while (lo < hi) { int mid = (lo + hi) >> 1; if (batch[mid] < g) lo = mid + 1; else hi = mid; }
  glo[g] = lo;
}

// ---------- mean pool, stage 1: (G x PS) grid, each block sums one slice of one
// graph's contiguous node segment into partial[g][s][64]. Deterministic, no atomics.
#define PS 24
__global__ void __launch_bounds__(256)
pool1(const float* __restrict__ acc, const int* __restrict__ glo,
      float* __restrict__ partial, int G)
{
  const int g = blockIdx.x;
  const int s = blockIdx.y;
  const int lane = threadIdx.x & 63;
  const int w = threadIdx.x >> 6;
  const int lo = glo[g], hi = glo[g + 1];
  const int len = hi - lo;
  const int a = lo + (int)(((long long)len * s) / PS);
  const int b = lo + (int)(((long long)len * (s + 1)) / PS);
  float sum = 0.f;
  for (int n = a + w; n < b; n += 4) sum += acc[(size_t)n * 64 + lane];
  __shared__ float red[4][64];
  red[w][lane] = sum;
  __syncthreads();
  if (w == 0)
    partial[((size_t)g * PS + s) * 64 + lane] =
        red[0][lane] + red[1][lane] + red[2][lane] + red[3][lane];
}

// stage 2: reduce PS slices, divide by segment length
__global__ void pool2(const float* __restrict__ partial, const int* __restrict__ glo,
                      float* __restrict__ out, int G)
{
  const int g = blockIdx.x;
  const int lane = threadIdx.x;   // 64 threads
  float t = 0.f;
#pragma unroll
  for (int s = 0; s < PS; ++s) t += partial[((size_t)g * PS + s) * 64 + lane];
  const int len = glo[g + 1] - glo[g];
  out[(size_t)g * 64 + lane] = t / fmaxf((float)len, 1.0f);
}

// ---------- launch ----------
extern "C" void kernel_launch(void* const* d_in, const int* in_sizes, int n_in,
                              void* d_out, int out_size, void* d_ws, size_t ws_size,
                              hipStream_t stream)
{
  const float* x     = (const float*)d_in[0];
  const int*   ei    = (const int*)d_in[1];
  const int*   etype = (const int*)d_in[2];
  const int*   batch = (const int*)d_in[3];
  const float* W1    = (const float*)d_in[4];
  const float* root1 = (const float*)d_in[5];
  const float* b1    = (const float*)d_in[6];
  const float* W2    = (const float*)d_in[7];
  const float* root2 = (const float*)d_in[8];
  const float* b2    = (const float*)d_in[9];

  const int N = in_sizes[0] / 64;
  const int E = in_sizes[1] / 2;
  const int R = in_sizes[4] / (64 * 64);
  const int G = out_size / 64;
  const int* srcp = ei;
  const int* dstp = ei + E;
  const int n2 = N * R;   // (dst,rel) bins

  // workspace carve-up (256B aligned)
  char* ws = (char*)d_ws;
  size_t off = 0;
  auto carve = [&](size_t bytes) -> void* {
    void* p = ws + off; off = (off + bytes + 255) & ~(size_t)255; return p;
  };
  float*          inv     = (float*)carve((size_t)n2 * 4);
  float*          accA    = (float*)carve((size_t)N * 64 * 4);
  float*          accB    = (float*)carve((size_t)N * 64 * 4);
  unsigned short* Y       = (unsigned short*)carve((size_t)N * R * 64 * 2);
  int*            eptr8   = (int*)carve((size_t)(n2 + 1) * 4);
  unsigned*       entry   = (unsigned*)carve((size_t)E * 4);
  int*            bsum    = (int*)carve(1024 * 4);
  int*            glo     = (int*)carve((size_t)(G + 1) * 4);
  float*          partial = (float*)carve((size_t)G * PS * 64 * 4);
  // dead-before-first-write aliases (same stream ⇒ ordered):
  //   rank[E] (u16) lives only until scatter_edges; accA first written by transform L1.
  //   cnt[n2] (i32) lives only until scan3/invert;  accB first written by transform L2.
  unsigned short* rank = (unsigned short*)accA;
  int*            cnt  = (int*)accB;
  (void)ws_size; (void)n_in;

  const int nb2 = (n2 + SCAN_T * SCAN_E - 1) / (SCAN_T * SCAN_E);

  // ---- CSR build: 1 atomic per edge total ----
  zero_i32<<<(n2 + 255) / 256, 256, 0, stream>>>(cnt, n2);
  count_rank<<<(E + 255) / 256, 256, 0, stream>>>(dstp, etype, cnt, rank, E);
  invert_cnt<<<(n2 + 255) / 256, 256, 0, stream>>>(cnt, inv, n2);
  scan1<<<nb2, SCAN_T, 0, stream>>>(cnt, bsum, n2);
  scan2<<<1, SCAN_T, 0, stream>>>(bsum, eptr8, nb2, n2);
  scan3<<<nb2, SCAN_T, 0, stream>>>(cnt, bsum, eptr8, n2);
  scatter_edges<<<(E + 255) / 256, 256, 0, stream>>>(srcp, dstp, etype, eptr8, rank, entry, E);

  dim3 tgrid(128, R + 1);
  const int aggBlocks = (N * 64 + 255) / 256;

  // ---- layer 1 ----
  transform<<<tgrid, 256, 0, stream>>>(x, W1, root1, b1, Y, accA, N, R, 0);
  edge_agg_csr<<<aggBlocks, 256, 0, stream>>>(Y, eptr8, entry, inv, accA, N);

  // ---- layer 2 (relu fused into transform's input read) ----
  transform<<<tgrid, 256, 0, stream>>>(accA, W2, root2, b2, Y, accB, N, R, 1);
  edge_agg_csr<<<aggBlocks, 256, 0, stream>>>(Y, eptr8, entry, inv, accB, N);

  // ---- global mean pool (two-stage, parallel) ----
  glo_bounds<<<1, 128, 0, stream>>>(batch, glo, N, G);
  dim3 pgrid(G, PS);
  pool1<<<pgrid, 256, 0, stream>>>(accB, glo, partial, G);
  pool2<<<G, 64, 0, stream>>>(partial, glo, (float*)d_out, G);
}

// Round 3
// 463.554 us; speedup vs baseline: 1.6482x; 1.0923x over previous
//
#include <hip/hip_runtime.h>
#include <stdint.h>

// ---------- types ----------
typedef __attribute__((ext_vector_type(8))) short short8;
typedef __attribute__((ext_vector_type(4))) float floatx4;

__device__ inline float bf2f(unsigned short u) {
  union { unsigned int i; float f; } v; v.i = ((unsigned int)u) << 16; return v.f;
}
__device__ inline unsigned short f2bf(float f) {
  union { float f; unsigned int i; } v; v.f = f;
  unsigned int r = v.i + 0x7FFFu + ((v.i >> 16) & 1u);  // round-nearest-even
  return (unsigned short)(r >> 16);
}

// ---------- utility ----------
__global__ void zero_i32(int* __restrict__ p, int n) {
  int i = blockIdx.x * blockDim.x + threadIdx.x;
  if (i < n) p[i] = 0;
}

// ---- CSR build, pass 1: per-(dst,rel) histogram; atomic return value IS the
//      edge's rank within its bin (order nondeterministic, but we only sum). ----
__global__ void count_rank(const int* __restrict__ dst, const int* __restrict__ et,
                           int* __restrict__ cnt, unsigned short* __restrict__ rank,
                           int E) {
  int e = blockIdx.x * blockDim.x + threadIdx.x;
  if (e < E) {
    int idx = dst[e] * 8 + et[e];
    rank[e] = (unsigned short)atomicAdd(&cnt[idx], 1);
  }
}

// inv[i] = 1/max(cnt[i],1)  (mean weights; no atomic float accumulation needed)
__global__ void invert_cnt(const int* __restrict__ cnt, float* __restrict__ inv, int n) {
  int i = blockIdx.x * blockDim.x + threadIdx.x;
  if (i < n) inv[i] = 1.0f / fmaxf((float)cnt[i], 1.0f);
}

// ---------- exclusive scan of cnt[n2] -> eptr8[n2] (+eptr8[n2]=E) ----------
#define SCAN_T 256
#define SCAN_E 4   // 1024 elems per block

__global__ void scan1(const int* __restrict__ cnt, int* __restrict__ bsum, int n) {
  __shared__ int lds[SCAN_T];
  int base = blockIdx.x * (SCAN_T * SCAN_E);
  int tid = threadIdx.x;
  int s = 0;
#pragma unroll
  for (int j = 0; j < SCAN_E; ++j) {
    int i = base + tid * SCAN_E + j;
    if (i < n) s += cnt[i];
  }
  lds[tid] = s; __syncthreads();
  for (int off = SCAN_T / 2; off > 0; off >>= 1) {
    if (tid < off) lds[tid] += lds[tid + off];
    __syncthreads();
  }
  if (tid == 0) bsum[blockIdx.x] = lds[0];
}

// parallel single-block exclusive scan over bsum[nb] (nb <= 1024)
__global__ void scan2(int* __restrict__ bsum, int* __restrict__ eptr, int nb, int n) {
  __shared__ int lds[SCAN_T];
  int tid = threadIdx.x;
  int loc[4]; int s = 0;
#pragma unroll
  for (int j = 0; j < 4; ++j) {
    int i = tid * 4 + j;
    loc[j] = (i < nb) ? bsum[i] : 0; s += loc[j];
  }
  lds[tid] = s; __syncthreads();
  for (int off = 1; off < SCAN_T; off <<= 1) {   // Hillis-Steele inclusive
    int v = (tid >= off) ? lds[tid - off] : 0;
    __syncthreads();
    lds[tid] += v;
    __syncthreads();
  }
  int run = (tid > 0 ? lds[tid - 1] : 0);
#pragma unroll
  for (int j = 0; j < 4; ++j) {
    int i = tid * 4 + j;
    if (i < nb) { int v = loc[j]; bsum[i] = run; run += v; }
  }
  if (tid == 0) eptr[n] = lds[SCAN_T - 1];   // total = E
}

__global__ void scan3(const int* __restrict__ cnt, const int* __restrict__ bsum,
                      int* __restrict__ eptr, int n) {
  __shared__ int lds[SCAN_T];
  int base = blockIdx.x * (SCAN_T * SCAN_E);
  int tid = threadIdx.x;
  int loc[SCAN_E]; int s = 0;
#pragma unroll
  for (int j = 0; j < SCAN_E; ++j) {
    int i = base + tid * SCAN_E + j;
    loc[j] = (i < n) ? cnt[i] : 0; s += loc[j];
  }
  lds[tid] = s; __syncthreads();
  for (int off = 1; off < SCAN_T; off <<= 1) {   // Hillis-Steele inclusive
    int v = (tid >= off) ? lds[tid - off] : 0;
    __syncthreads();
    lds[tid] += v;
    __syncthreads();
  }
  int run = (tid > 0 ? lds[tid - 1] : 0) + bsum[blockIdx.x];
#pragma unroll
  for (int j = 0; j < SCAN_E; ++j) {
    int i = base + tid * SCAN_E + j;
    if (i < n) { eptr[i] = run; run += loc[j]; }
  }
}

// ---- CSR build, pass 2: deterministic placement, NO atomics.
//      position = eptr8[d*8+r] + rank[e]; entry = (src<<3)|rel ----
__global__ void scatter_edges(const int* __restrict__ src, const int* __restrict__ dst,
                              const int* __restrict__ et, const int* __restrict__ eptr8,
                              const unsigned short* __restrict__ rank,
                              unsigned* __restrict__ entry, int E) {
  int e = blockIdx.x * blockDim.x + threadIdx.x;
  if (e < E) {
    int d = dst[e], r = et[e];
    int p = eptr8[d * 8 + r] + (int)rank[e];
    entry[p] = ((unsigned)src[e] << 3) | (unsigned)r;
  }
}

// ---------- weight prep: all 9 matrices (8 W + root) -> bf16, MFMA-fragment-
// swizzled layout so transform reads each lane's 8-elem fragment as one
// ds_read_b128: Wb[m][ ((kc*4+q)*4+nt)*16+lc ][j],  k=kc*32+q*8+j, c=nt*16+lc
__global__ void conv_weights(const float* __restrict__ W, const float* __restrict__ root,
                             unsigned short* __restrict__ Wb, int R) {
  int i = blockIdx.x * blockDim.x + threadIdx.x;
  int total = (R + 1) * 4096;
  if (i >= total) return;
  int m = i >> 12, rem = i & 4095, k = rem >> 6, c = rem & 63;
  float w = (m < R) ? W[(size_t)m * 4096 + k * 64 + c] : root[(size_t)k * 64 + c];
  int kc = k >> 5, q = (k >> 3) & 3, j = k & 7, nt = c >> 4, lcv = c & 15;
  Wb[(size_t)m * 4096 + (size_t)(((kc * 4 + q) * 4 + nt) * 16 + lcv) * 8 + j] = f2bf(w);
}

// ---------- fused transform: each block stages a slice of weight matrices in LDS,
// loads+converts each A-tile ONCE, loops groups inside.
//   y=0: groups 0..3 (W0-3, 32KB LDS)   y=1: groups 4..8 (W4-7 + root, 40KB LDS)
// Y[n][g*64+c] = sum_d act(X[n][d]) * W_g[d][c]   (g<8, bf16 out)
// acc[n][c]    = b[c] + sum_d act(X[n][d]) * root[d][c]  (g==8)
__global__ void __launch_bounds__(256)
transform_fused(const float* __restrict__ X, const unsigned short* __restrict__ Wb,
                const float* __restrict__ bias, unsigned short* __restrict__ Y,
                float* __restrict__ acc, int N, int relu_in)
{
  const int gy   = blockIdx.y;
  const int base = gy ? 4 : 0;
  const int ng   = gy ? 5 : 4;
  __shared__ __align__(16) unsigned short wlds[5 * 4096];   // 40 KB -> 4 blocks/CU

  // cooperative stage: ng*4096 ushorts, 16B chunks (exact multiple of 256 threads)
  const unsigned short* wsrc = Wb + (size_t)base * 4096;
  const int nel = ng * 4096;
  for (int i = threadIdx.x * 8; i < nel; i += 256 * 8)
    *(uint4*)&wlds[i] = *(const uint4*)&wsrc[i];
  __syncthreads();

  const int lane = threadIdx.x & 63;
  const int wave = threadIdx.x >> 6;
  const int lc   = lane & 15;
  const int quad = lane >> 4;
  const int tiles  = (N + 15) >> 4;
  const int stride = gridDim.x * 4;

  for (int t = blockIdx.x * 4 + wave; t < tiles; t += stride) {
    const int nb  = t << 4;
    const int row = min(nb + lc, N - 1);
    const float* xr = X + (size_t)row * 64;
    short8 a0, a1;
#pragma unroll
    for (int j = 0; j < 8; ++j) {
      float v0 = xr[quad * 8 + j];
      float v1 = xr[32 + quad * 8 + j];
      if (relu_in) { v0 = fmaxf(v0, 0.f); v1 = fmaxf(v1, 0.f); }
      a0[j] = (short)f2bf(v0);
      a1[j] = (short)f2bf(v1);
    }
    for (int gi = 0; gi < ng; ++gi) {
      const int g = base + gi;
#pragma unroll
      for (int nt = 0; nt < 4; ++nt) {
        short8 b0 = *(const short8*)&wlds[gi * 4096 + (((0 * 4 + quad) * 4 + nt) * 16 + lc) * 8];
        short8 b1 = *(const short8*)&wlds[gi * 4096 + (((1 * 4 + quad) * 4 + nt) * 16 + lc) * 8];
        floatx4 d = {0.f, 0.f, 0.f, 0.f};
        d = __builtin_amdgcn_mfma_f32_16x16x32_bf16(a0, b0, d, 0, 0, 0);
        d = __builtin_amdgcn_mfma_f32_16x16x32_bf16(a1, b1, d, 0, 0, 0);
        const int c = nt * 16 + lc;
        if (g < 8) {
#pragma unroll
          for (int i = 0; i < 4; ++i) {
            int r_ = nb + quad * 4 + i;
            if (r_ < N) Y[(size_t)r_ * 512 + g * 64 + c] = f2bf(d[i]);
          }
        } else {
          float bv = bias[c];
#pragma unroll
          for (int i = 0; i < 4; ++i) {
            int r_ = nb + quad * 4 + i;
            if (r_ < N) acc[(size_t)r_ * 64 + c] = d[i] + bv;
          }
        }
      }
    }
  }
}

// ---------- CSR edge aggregation: one wave owns one dst node. No atomics.
// acc[d][lane] += sum_{e in seg(d)} Y[src_e][rel_e*64+lane] * inv[d*8+rel_e]
__global__ void __launch_bounds__(256)
edge_agg_csr(const unsigned short* __restrict__ Y, const int* __restrict__ eptr8,
             const unsigned* __restrict__ entry, const float* __restrict__ inv,
             float* __restrict__ acc, int N)
{
  const int wid  = (blockIdx.x * blockDim.x + threadIdx.x) >> 6;
  const int lane = threadIdx.x & 63;
  if (wid >= N) return;
  const int lo = eptr8[wid * 8], hi = eptr8[wid * 8 + 8];
  const float invv = inv[(size_t)wid * 8 + (lane & 7)];   // lanes 0..7 hold the 8 rel weights
  float sum = 0.f;
  int e = lo;
  for (; e + 4 <= hi; e += 4) {
    unsigned en0 = entry[e], en1 = entry[e + 1], en2 = entry[e + 2], en3 = entry[e + 3];
    float v0 = bf2f(Y[(size_t)(en0 >> 3) * 512 + (en0 & 7) * 64 + lane]);
    float v1 = bf2f(Y[(size_t)(en1 >> 3) * 512 + (en1 & 7) * 64 + lane]);
    float v2 = bf2f(Y[(size_t)(en2 >> 3) * 512 + (en2 & 7) * 64 + lane]);
    float v3 = bf2f(Y[(size_t)(en3 >> 3) * 512 + (en3 & 7) * 64 + lane]);
    sum += v0 * __shfl(invv, (int)(en0 & 7)) + v1 * __shfl(invv, (int)(en1 & 7))
         + v2 * __shfl(invv, (int)(en2 & 7)) + v3 * __shfl(invv, (int)(en3 & 7));
  }
  for (; e < hi; ++e) {
    unsigned en = entry[e];
    float v = bf2f(Y[(size_t)(en >> 3) * 512 + (en & 7) * 64 + lane]);
    sum += v * __shfl(invv, (int)(en & 7));
  }
  acc[(size_t)wid * 64 + lane] += sum;
}

// graph segment boundaries from sorted batch: glo[g] = lower_bound(batch, g); glo[G]=N
__global__ void glo_bounds(const int* __restrict__ batch, int* __restrict__ glo,
                           int N, int G) {
  int g = blockIdx.x * blockDim.x + threadIdx.x;
  if (g > G) return;
  if (g == G) { glo[G] = N; return; }
  int lo = 0, hi = N;
  while (lo < hi) { int mid = (lo + hi) >> 1; if (batch[mid] < g) lo = mid + 1; else hi = mid; }
  glo[g] = lo;
}

// ---------- mean pool, stage 1: (G x PS) grid, each block sums one slice of one
// graph's contiguous node segment into partial[g][s][64]. Deterministic, no atomics.
#define PS 24
__global__ void __launch_bounds__(256)
pool1(const float* __restrict__ acc, const int* __restrict__ glo,
      float* __restrict__ partial, int G)
{
  const int g = blockIdx.x;
  const int s = blockIdx.y;
  const int lane = threadIdx.x & 63;
  const int w = threadIdx.x >> 6;
  const int lo = glo[g], hi = glo[g + 1];
  const int len = hi - lo;
  const int a = lo + (int)(((long long)len * s) / PS);
  const int b = lo + (int)(((long long)len * (s + 1)) / PS);
  float sum = 0.f;
  for (int n = a + w; n < b; n += 4) sum += acc[(size_t)n * 64 + lane];
  __shared__ float red[4][64];
  red[w][lane] = sum;
  __syncthreads();
  if (w == 0)
    partial[((size_t)g * PS + s) * 64 + lane] =
        red[0][lane] + red[1][lane] + red[2][lane] + red[3][lane];
}

// stage 2: reduce PS slices, divide by segment length
__global__ void pool2(const float* __restrict__ partial, const int* __restrict__ glo,
                      float* __restrict__ out, int G)
{
  const int g = blockIdx.x;
  const int lane = threadIdx.x;   // 64 threads
  float t = 0.f;
#pragma unroll
  for (int s = 0; s < PS; ++s) t += partial[((size_t)g * PS + s) * 64 + lane];
  const int len = glo[g + 1] - glo[g];
  out[(size_t)g * 64 + lane] = t / fmaxf((float)len, 1.0f);
}

// ---------- launch ----------
extern "C" void kernel_launch(void* const* d_in, const int* in_sizes, int n_in,
                              void* d_out, int out_size, void* d_ws, size_t ws_size,
                              hipStream_t stream)
{
  const float* x     = (const float*)d_in[0];
  const int*   ei    = (const int*)d_in[1];
  const int*   etype = (const int*)d_in[2];
  const int*   batch = (const int*)d_in[3];
  const float* W1    = (const float*)d_in[4];
  const float* root1 = (const float*)d_in[5];
  const float* b1    = (const float*)d_in[6];
  const float* W2    = (const float*)d_in[7];
  const float* root2 = (const float*)d_in[8];
  const float* b2    = (const float*)d_in[9];

  const int N = in_sizes[0] / 64;
  const int E = in_sizes[1] / 2;
  const int R = in_sizes[4] / (64 * 64);   // == 8
  const int G = out_size / 64;
  const int* srcp = ei;
  const int* dstp = ei + E;
  const int n2 = N * R;   // (dst,rel) bins

  // workspace carve-up (256B aligned)
  char* ws = (char*)d_ws;
  size_t off = 0;
  auto carve = [&](size_t bytes) -> void* {
    void* p = ws + off; off = (off + bytes + 255) & ~(size_t)255; return p;
  };
  float*          inv     = (float*)carve((size_t)n2 * 4);
  float*          accA    = (float*)carve((size_t)N * 64 * 4);
  float*          accB    = (float*)carve((size_t)N * 64 * 4);
  unsigned short* Y       = (unsigned short*)carve((size_t)N * R * 64 * 2);
  int*            eptr8   = (int*)carve((size_t)(n2 + 1) * 4);
  unsigned*       entry   = (unsigned*)carve((size_t)E * 4);
  int*            bsum    = (int*)carve(1024 * 4);
  int*            glo     = (int*)carve((size_t)(G + 1) * 4);
  float*          partial = (float*)carve((size_t)G * PS * 64 * 4);
  unsigned short* Wb      = (unsigned short*)carve((size_t)(R + 1) * 4096 * 2);
  // dead-before-first-write aliases (same stream ⇒ ordered):
  //   rank[E] (u16) lives only until scatter_edges; accA first written by transform L1.
  //   cnt[n2] (i32) lives only until scan3/invert;  accB first written by transform L2.
  unsigned short* rank = (unsigned short*)accA;
  int*            cnt  = (int*)accB;
  (void)ws_size; (void)n_in;

  const int nb2 = (n2 + SCAN_T * SCAN_E - 1) / (SCAN_T * SCAN_E);

  // ---- CSR build: 1 atomic per edge total ----
  zero_i32<<<(n2 + 255) / 256, 256, 0, stream>>>(cnt, n2);
  count_rank<<<(E + 255) / 256, 256, 0, stream>>>(dstp, etype, cnt, rank, E);
  invert_cnt<<<(n2 + 255) / 256, 256, 0, stream>>>(cnt, inv, n2);
  scan1<<<nb2, SCAN_T, 0, stream>>>(cnt, bsum, n2);
  scan2<<<1, SCAN_T, 0, stream>>>(bsum, eptr8, nb2, n2);
  scan3<<<nb2, SCAN_T, 0, stream>>>(cnt, bsum, eptr8, n2);
  scatter_edges<<<(E + 255) / 256, 256, 0, stream>>>(srcp, dstp, etype, eptr8, rank, entry, E);

  const int tiles = (N + 15) >> 4;
  dim3 tgrid((tiles + 3) / 4, 2);
  const int aggBlocks = (N * 64 + 255) / 256;
  const int wblocks = ((R + 1) * 4096 + 255) / 256;

  // ---- layer 1 ----
  conv_weights<<<wblocks, 256, 0, stream>>>(W1, root1, Wb, R);
  transform_fused<<<tgrid, 256, 0, stream>>>(x, Wb, b1, Y, accA, N, 0);
  edge_agg_csr<<<aggBlocks, 256, 0, stream>>>(Y, eptr8, entry, inv, accA, N);

  // ---- layer 2 (relu fused into transform's input read) ----
  conv_weights<<<wblocks, 256, 0, stream>>>(W2, root2, Wb, R);
  transform_fused<<<tgrid, 256, 0, stream>>>(accA, Wb, b2, Y, accB, N, 1);
  edge_agg_csr<<<aggBlocks, 256, 0, stream>>>(Y, eptr8, entry, inv, accB, N);

  // ---- global mean pool (two-stage, parallel) ----
  glo_bounds<<<1, 128, 0, stream>>>(batch, glo, N, G);
  dim3 pgrid(G, PS);
  pool1<<<pgrid, 256, 0, stream>>>(accB, glo, partial, G);
  pool2<<<G, 64, 0, stream>>>(partial, glo, (float*)d_out, G);
}